// Round 6
// baseline (74.178 us; speedup 1.0000x reference)
//
#include <hip/hip_runtime.h>
#include <hip/hip_cooperative_groups.h>

namespace cg = cooperative_groups;

#define NSAMP 65536
#define DTF 1e-5f

// ---------- complex helpers (float2 = complex64) ----------
__device__ __forceinline__ float2 cmul(float2 a, float2 b) {
    return make_float2(a.x * b.x - a.y * b.y, a.x * b.y + a.y * b.x);
}
__device__ __forceinline__ float2 cmac(float2 c, float2 a, float2 b) {
    c.x += a.x * b.x - a.y * b.y;
    c.y += a.x * b.y + a.y * b.x;
    return c;
}
__device__ __forceinline__ float2 cmulc(float2 a, float2 b) { // a * conj(b)
    return make_float2(a.x * b.x + a.y * b.y, a.y * b.x - a.x * b.y);
}

// ---------- 4x4 complex matmul C = A*B (row-major, 16 float2) ----------
__device__ __forceinline__ void mm4(const float2* A, const float2* B, float2* C) {
#pragma unroll
    for (int a = 0; a < 4; ++a) {
#pragma unroll
        for (int b = 0; b < 4; ++b) {
            float2 acc = cmul(A[a * 4 + 0], B[0 * 4 + b]);
            acc = cmac(acc, A[a * 4 + 1], B[1 * 4 + b]);
            acc = cmac(acc, A[a * 4 + 2], B[2 * 4 + b]);
            acc = cmac(acc, A[a * 4 + 3], B[3 * 4 + b]);
            C[a * 4 + b] = acc;
        }
    }
}

// two matvecs: w[0..3] <- M*w[0..3], w[4..7] <- M*w[4..7]
__device__ __forceinline__ void mv2(const float2* M, float2* w) {
    float2 r[8];
#pragma unroll
    for (int a = 0; a < 4; ++a) {
        float2 a0 = cmul(M[a * 4 + 0], w[0]);
        float2 a1 = cmul(M[a * 4 + 0], w[4]);
#pragma unroll
        for (int k = 1; k < 4; ++k) {
            a0 = cmac(a0, M[a * 4 + k], w[k]);
            a1 = cmac(a1, M[a * 4 + k], w[4 + k]);
        }
        r[a] = a0;
        r[4 + a] = a1;
    }
#pragma unroll
    for (int i = 0; i < 8; ++i) w[i] = r[i];
}

// ---------- 16-float2 (128B) moves (LDS or global, 16B-aligned) ----------
__device__ __forceinline__ void ld16(float2* X, const float2* p) {
    const float4* q = (const float4*)p;
#pragma unroll
    for (int i = 0; i < 8; ++i) {
        float4 t = q[i];
        X[2 * i]     = make_float2(t.x, t.y);
        X[2 * i + 1] = make_float2(t.z, t.w);
    }
}
__device__ __forceinline__ void st16(float2* p, const float2* X) {
    float4* q = (float4*)p;
#pragma unroll
    for (int i = 0; i < 8; ++i)
        q[i] = make_float4(X[2 * i].x, X[2 * i].y, X[2 * i + 1].x, X[2 * i + 1].y);
}

// ---------- U = exp(-i*dt*H) in registers: s=2 scaling, order-6 Taylor ----------
__device__ __forceinline__ void expmU(float uxi, float uyi, float v1, float v2,
                                      float J, float2* X) {
    const float twopi = 6.2831855f;
    float d0 = twopi * (0.5f * (v1 + v2) + 0.25f * J);
    float d1 = twopi * (0.5f * (v1 - v2) - 0.25f * J);
    float d2 = twopi * (0.5f * (v2 - v1) - 0.25f * J);
    float d3 = twopi * (-0.5f * (v1 + v2) + 0.25f * J);
    float g  = twopi * 0.5f * J;
    float cr = 0.5f * uxi;
    float ci = -0.5f * uyi;

    // H (Hermitian):
    // [d0,  c,  c,  0 ]
    // [c*, d1,  g,  c ]
    // [c*,  g, d2,  c ]
    // [ 0, c*, c*, d3 ]
    float2 H[16];
    H[0]  = make_float2(d0, 0.f);  H[1]  = make_float2(cr, ci);
    H[2]  = make_float2(cr, ci);   H[3]  = make_float2(0.f, 0.f);
    H[4]  = make_float2(cr, -ci);  H[5]  = make_float2(d1, 0.f);
    H[6]  = make_float2(g, 0.f);   H[7]  = make_float2(cr, ci);
    H[8]  = make_float2(cr, -ci);  H[9]  = make_float2(g, 0.f);
    H[10] = make_float2(d2, 0.f);  H[11] = make_float2(cr, ci);
    H[12] = make_float2(0.f, 0.f); H[13] = make_float2(cr, -ci);
    H[14] = make_float2(cr, -ci);  H[15] = make_float2(d3, 0.f);

    // A = -i * (dt/2) * H :  (-i)*(hr + i*hi) = hi - i*hr
    const float s = DTF * 0.5f;
    float2 A[16];
#pragma unroll
    for (int k = 0; k < 16; ++k) A[k] = make_float2(s * H[k].y, -s * H[k].x);

    // order-6 Taylor via Horner: X = I + A/6; X = I + (A/k)*X, k=5..1
#pragma unroll
    for (int k = 0; k < 16; ++k)
        X[k] = make_float2(A[k].x * (1.f / 6.f), A[k].y * (1.f / 6.f));
    X[0].x += 1.f; X[5].x += 1.f; X[10].x += 1.f; X[15].x += 1.f;
#pragma unroll
    for (int kk = 5; kk >= 1; --kk) {
        float2 Z[16];
        mm4(A, X, Z);
        float r = 1.0f / (float)kk;
#pragma unroll
        for (int k = 0; k < 16; ++k) X[k] = make_float2(Z[k].x * r, Z[k].y * r);
        X[0].x += 1.f; X[5].x += 1.f; X[10].x += 1.f; X[15].x += 1.f;
    }
    // square once (undo the /2 scaling)
    {
        float2 Z[16];
        mm4(X, X, Z);
#pragma unroll
        for (int k = 0; k < 16; ++k) X[k] = Z[k];
    }
}

// ---------- barrier-free 64-lane inclusive matrix scan via shfl_up ----------
// combine newer-on-the-left: X_l <- X_l * X_{l-off}
__device__ __forceinline__ void wave_scan(float2* X, int lane) {
#pragma unroll
    for (int off = 1; off < 64; off <<= 1) {
        float2 Y[16];
#pragma unroll
        for (int j = 0; j < 16; ++j) {
            Y[j].x = __shfl_up(X[j].x, (unsigned)off, 64);
            Y[j].y = __shfl_up(X[j].y, (unsigned)off, 64);
        }
        if (lane >= off) {
            float2 Z[16];
            mm4(X, Y, Z);
#pragma unroll
            for (int j = 0; j < 16; ++j) X[j] = Z[j];
        }
    }
}

// progressive cross-wave combine inside a 256-thread block.
// WT[w] (w=0..2) holds wave w's total. Wave w multiplies by WT[w-1..0].
// REQUIRES: no thread is still reading WT from a previous use (barrier before).
__device__ __forceinline__ void block_combine(float2* X, float2 (*WT)[16],
                                              int w, int lane) {
    if (w < 3 && lane == 63) st16(&WT[w][0], X);
    __syncthreads();
    for (int k = w - 1; k >= 0; --k) {
        float2 Y[16], Z[16];
        ld16(Y, &WT[k][0]);
        mm4(X, Y, Z);
#pragma unroll
        for (int j = 0; j < 16; ++j) X[j] = Z[j];
    }
}

// measurement: wv = cols 0,3 of P -> Re(0.25*(rho01+rho02+rho13+rho23))
__device__ __forceinline__ float measure(const float2* wv) {
    float re0 = cmulc(wv[0], wv[1]).x + cmulc(wv[0], wv[2]).x +
                cmulc(wv[1], wv[3]).x + cmulc(wv[2], wv[3]).x;
    float re3 = cmulc(wv[4], wv[5]).x + cmulc(wv[4], wv[6]).x +
                cmulc(wv[5], wv[7]).x + cmulc(wv[6], wv[7]).x;
    return 0.25f * (re0 - re3);
}

// ---------- PATH 1: fused single-dispatch cooperative kernel ----------
__global__ __launch_bounds__(256, 1) void k_fused(
    const float* __restrict__ ux, const float* __restrict__ uy,
    const float* __restrict__ v1p, const float* __restrict__ v2p,
    const float* __restrict__ Jp, float2* __restrict__ T,
    float* __restrict__ out) {
    __shared__ __align__(16) float2 WT[3][16];
    __shared__ __align__(16) float2 WB[8];

    cg::grid_group grid = cg::this_grid();
    int b = blockIdx.x, t = threadIdx.x;
    int lane = t & 63, w = t >> 6;
    int n = b * 256 + t;

    // phase 1: per-sample propagator + in-block inclusive scan (X stays in regs)
    float2 X[16];
    expmU(ux[n], uy[n], *v1p, *v2p, *Jp, X);
    wave_scan(X, lane);
    block_combine(X, WT, w, lane); // X = U_n ... U_{256b}
    if (t == 255) st16(T + (size_t)b * 16, X);
    __threadfence();
    grid.sync();

    // phase 2: every block redundantly scans the 256 block totals
    float2 Xt[16];
    ld16(Xt, T + (size_t)t * 16);
    wave_scan(Xt, lane);
    block_combine(Xt, WT, w, lane); // thread t: T_t * ... * T_0
    if (b == 0) {
        if (t == 0) {
#pragma unroll
            for (int i = 0; i < 8; ++i) WB[i] = make_float2(0.f, 0.f);
            WB[0] = make_float2(1.f, 0.f); // col0 of I
            WB[7] = make_float2(1.f, 0.f); // col3 of I
        }
    } else if (t == b - 1) { // inclusive up to b-1 = exclusive prefix for block b
#pragma unroll
        for (int a = 0; a < 4; ++a) {
            WB[a]     = Xt[a * 4 + 0];
            WB[4 + a] = Xt[a * 4 + 3];
        }
    }
    __syncthreads();

    // phase 3: apply prefix cols, measure, write
    float2 wv[8];
#pragma unroll
    for (int i = 0; i < 8; ++i) wv[i] = WB[i];
    mv2(X, wv);
    out[n] = measure(wv);
}

// ---------- PATH 2 (fallback): 2 plain dispatches ----------
// kA: block totals only
__global__ __launch_bounds__(256) void kA_tot(
    const float* __restrict__ ux, const float* __restrict__ uy,
    const float* __restrict__ v1p, const float* __restrict__ v2p,
    const float* __restrict__ Jp, float2* __restrict__ T) {
    __shared__ __align__(16) float2 WT[3][16];
    int b = blockIdx.x, t = threadIdx.x;
    int lane = t & 63, w = t >> 6;
    int n = b * 256 + t;
    float2 X[16];
    expmU(ux[n], uy[n], *v1p, *v2p, *Jp, X);
    wave_scan(X, lane);
    block_combine(X, WT, w, lane);
    if (t == 255) st16(T + (size_t)b * 16, X);
}

// kB: redundant totals-scan (prefix cols to LDS) -> recompute + apply + measure
__global__ __launch_bounds__(256) void kB_all(
    const float* __restrict__ ux, const float* __restrict__ uy,
    const float* __restrict__ v1p, const float* __restrict__ v2p,
    const float* __restrict__ Jp, const float2* __restrict__ T,
    float* __restrict__ out) {
    __shared__ __align__(16) float2 WT[3][16];
    __shared__ __align__(16) float2 WB[8];
    int b = blockIdx.x, t = threadIdx.x;
    int lane = t & 63, w = t >> 6;

    // totals scan first (minimizes register liveness overlap)
    float2 Xt[16];
    ld16(Xt, T + (size_t)t * 16);
    wave_scan(Xt, lane);
    block_combine(Xt, WT, w, lane);
    if (b == 0) {
        if (t == 0) {
#pragma unroll
            for (int i = 0; i < 8; ++i) WB[i] = make_float2(0.f, 0.f);
            WB[0] = make_float2(1.f, 0.f);
            WB[7] = make_float2(1.f, 0.f);
        }
    } else if (t == b - 1) {
#pragma unroll
        for (int a = 0; a < 4; ++a) {
            WB[a]     = Xt[a * 4 + 0];
            WB[4 + a] = Xt[a * 4 + 3];
        }
    }
    __syncthreads(); // WB fixed; also protects WT reuse below

    // per-sample propagator + in-block scan
    int n = b * 256 + t;
    float2 X[16];
    expmU(ux[n], uy[n], *v1p, *v2p, *Jp, X);
    wave_scan(X, lane);
    block_combine(X, WT, w, lane);

    float2 wv[8];
#pragma unroll
    for (int i = 0; i < 8; ++i) wv[i] = WB[i];
    mv2(X, wv);
    out[n] = measure(wv);
}

extern "C" void kernel_launch(void* const* d_in, const int* in_sizes, int n_in,
                              void* d_out, int out_size, void* d_ws, size_t ws_size,
                              hipStream_t stream) {
    const float* ux = (const float*)d_in[0];
    const float* uy = (const float*)d_in[1];
    const float* v1 = (const float*)d_in[2];
    const float* v2 = (const float*)d_in[3];
    const float* J  = (const float*)d_in[4];
    float* out = (float*)d_out;
    float2* T = (float2*)d_ws; // 256 * 128B = 32 KiB

    void* args[] = {(void*)&ux, (void*)&uy, (void*)&v1, (void*)&v2,
                    (void*)&J, (void*)&T, (void*)&out};
    hipError_t err = hipLaunchCooperativeKernel((const void*)k_fused, dim3(256),
                                                dim3(256), args, 0, stream);
    if (err != hipSuccess) {
        (void)hipGetLastError(); // clear sticky error state
        kA_tot<<<256, 256, 0, stream>>>(ux, uy, v1, v2, J, T);
        kB_all<<<256, 256, 0, stream>>>(ux, uy, v1, v2, J, T, out);
    }
}

// Round 7
// 24.265 us; speedup vs baseline: 3.0570x; 3.0570x over previous
//
#include <hip/hip_runtime.h>

#define NSAMP 65536
#define DTF 1e-5f

// packed complex: f2.x = re, f2.y = im ; ops lower to v_pk_fma_f32 (VOP3P)
typedef float f2 __attribute__((ext_vector_type(2)));

// (-b.im, b.re) — the "i*b" swizzle used to form packed complex FMA
__device__ __forceinline__ f2 ib(f2 b) { return (f2){-b.y, b.x}; }

// acc += a*b given precomputed bn = ib(b): two packed FMAs
__device__ __forceinline__ f2 cmac_p(f2 acc, f2 a, f2 b, f2 bn) {
    acc = a.y * bn + acc; // (-ay*by, ay*bx) + acc
    acc = a.x * b + acc;  // (ax*bx, ax*by) + ...
    return acc;
}

// ---------- 4x4 complex matmul C = A*B (row-major, 16 f2), packed ----------
__device__ __forceinline__ void mm4p(const f2* A, const f2* B, f2* C) {
    f2 BN[16];
#pragma unroll
    for (int i = 0; i < 16; ++i) BN[i] = ib(B[i]);
#pragma unroll
    for (int a = 0; a < 4; ++a) {
#pragma unroll
        for (int b = 0; b < 4; ++b) {
            f2 acc = (f2){0.f, 0.f};
#pragma unroll
            for (int k = 0; k < 4; ++k)
                acc = cmac_p(acc, A[a * 4 + k], B[k * 4 + b], BN[k * 4 + b]);
            C[a * 4 + b] = acc;
        }
    }
}

// two matvecs: w[0..3] <- M*w[0..3], w[4..7] <- M*w[4..7] (packed)
__device__ __forceinline__ void mv2p(const f2* M, f2* w) {
    f2 WN[8];
#pragma unroll
    for (int i = 0; i < 8; ++i) WN[i] = ib(w[i]);
    f2 r[8];
#pragma unroll
    for (int a = 0; a < 4; ++a) {
        f2 a0 = (f2){0.f, 0.f}, a1 = (f2){0.f, 0.f};
#pragma unroll
        for (int k = 0; k < 4; ++k) {
            a0 = cmac_p(a0, M[a * 4 + k], w[k], WN[k]);
            a1 = cmac_p(a1, M[a * 4 + k], w[4 + k], WN[4 + k]);
        }
        r[a] = a0;
        r[4 + a] = a1;
    }
#pragma unroll
    for (int i = 0; i < 8; ++i) w[i] = r[i];
}

// ---------- 16-f2 (128B) moves for 16B-aligned buffers ----------
__device__ __forceinline__ void ld16(f2* X, const f2* p) {
    const float4* q = (const float4*)p;
#pragma unroll
    for (int i = 0; i < 8; ++i) {
        float4 t = q[i];
        X[2 * i]     = (f2){t.x, t.y};
        X[2 * i + 1] = (f2){t.z, t.w};
    }
}
__device__ __forceinline__ void st16(f2* p, const f2* X) {
    float4* q = (float4*)p;
#pragma unroll
    for (int i = 0; i < 8; ++i)
        q[i] = make_float4(X[2 * i].x, X[2 * i].y, X[2 * i + 1].x, X[2 * i + 1].y);
}

// ---------- U = exp(-i*dt*H) in registers: s=2 scaling, order-6 Taylor ----------
__device__ __forceinline__ void expmU(float uxi, float uyi, float v1, float v2,
                                      float J, f2* X) {
    const float twopi = 6.2831855f;
    float d0 = twopi * (0.5f * (v1 + v2) + 0.25f * J);
    float d1 = twopi * (0.5f * (v1 - v2) - 0.25f * J);
    float d2 = twopi * (0.5f * (v2 - v1) - 0.25f * J);
    float d3 = twopi * (-0.5f * (v1 + v2) + 0.25f * J);
    float g  = twopi * 0.5f * J;
    float cr = 0.5f * uxi;
    float ci = -0.5f * uyi;

    // H (Hermitian):
    // [d0,  c,  c,  0 ]
    // [c*, d1,  g,  c ]
    // [c*,  g, d2,  c ]
    // [ 0, c*, c*, d3 ]
    f2 H[16];
    H[0]  = (f2){d0, 0.f};  H[1]  = (f2){cr, ci};
    H[2]  = (f2){cr, ci};   H[3]  = (f2){0.f, 0.f};
    H[4]  = (f2){cr, -ci};  H[5]  = (f2){d1, 0.f};
    H[6]  = (f2){g, 0.f};   H[7]  = (f2){cr, ci};
    H[8]  = (f2){cr, -ci};  H[9]  = (f2){g, 0.f};
    H[10] = (f2){d2, 0.f};  H[11] = (f2){cr, ci};
    H[12] = (f2){0.f, 0.f}; H[13] = (f2){cr, -ci};
    H[14] = (f2){cr, -ci};  H[15] = (f2){d3, 0.f};

    // A = -i * (dt/2) * H : (-i)*(hr + i*hi) = hi - i*hr
    const float s = DTF * 0.5f;
    f2 A[16];
#pragma unroll
    for (int k = 0; k < 16; ++k) A[k] = (f2){s * H[k].y, -s * H[k].x};

    // order-6 Taylor via Horner: X = I + A/6; X = I + (A/k)*X, k=5..1
#pragma unroll
    for (int k = 0; k < 16; ++k) X[k] = A[k] * (1.f / 6.f);
    X[0].x += 1.f; X[5].x += 1.f; X[10].x += 1.f; X[15].x += 1.f;
#pragma unroll
    for (int kk = 5; kk >= 1; --kk) {
        f2 Z[16];
        mm4p(A, X, Z);
        float r = 1.0f / (float)kk;
#pragma unroll
        for (int k = 0; k < 16; ++k) X[k] = Z[k] * r;
        X[0].x += 1.f; X[5].x += 1.f; X[10].x += 1.f; X[15].x += 1.f;
    }
    // square once (undo the /2 scaling)
    {
        f2 Z[16];
        mm4p(X, X, Z);
#pragma unroll
        for (int k = 0; k < 16; ++k) X[k] = Z[k];
    }
}

// ---------- barrier-free 64-lane inclusive matrix scan via shfl_up ----------
// combine newer-on-the-left: X_l <- X_l * X_{l-off}
__device__ __forceinline__ void wave_scan(f2* X, int lane) {
#pragma unroll
    for (int off = 1; off < 64; off <<= 1) {
        f2 Y[16];
#pragma unroll
        for (int j = 0; j < 16; ++j) {
            Y[j].x = __shfl_up(X[j].x, (unsigned)off, 64);
            Y[j].y = __shfl_up(X[j].y, (unsigned)off, 64);
        }
        if (lane >= off) {
            f2 Z[16];
            mm4p(X, Y, Z);
#pragma unroll
            for (int j = 0; j < 16; ++j) X[j] = Z[j];
        }
    }
}

// progressive cross-wave combine inside a 256-thread block.
// WT[w] (w=0..2) holds wave w's total. Wave w multiplies by WT[w-1..0].
__device__ __forceinline__ void block_combine(f2* X, f2 (*WT)[16],
                                              int w, int lane) {
    if (w < 3 && lane == 63) st16(&WT[w][0], X);
    __syncthreads();
    for (int k = w - 1; k >= 0; --k) {
        f2 Y[16], Z[16];
        ld16(Y, &WT[k][0]);
        mm4p(X, Y, Z);
#pragma unroll
        for (int j = 0; j < 16; ++j) X[j] = Z[j];
    }
}

// measurement: wv = cols 0,3 of P -> Re(0.25*(rho01+rho02+rho13+rho23))
// Re(a*conj(b)) = a.x*b.x + a.y*b.y
__device__ __forceinline__ float rec(f2 a, f2 b) { return a.x * b.x + a.y * b.y; }
__device__ __forceinline__ float measure(const f2* wv) {
    float re0 = rec(wv[0], wv[1]) + rec(wv[0], wv[2]) +
                rec(wv[1], wv[3]) + rec(wv[2], wv[3]);
    float re3 = rec(wv[4], wv[5]) + rec(wv[4], wv[6]) +
                rec(wv[5], wv[7]) + rec(wv[6], wv[7]);
    return 0.25f * (re0 - re3);
}

// ---------- kA: expm + in-block scan; store S (SoA planes) + block totals T ----------
__global__ __launch_bounds__(256) void kA_scan(
    const float* __restrict__ ux, const float* __restrict__ uy,
    const float* __restrict__ v1p, const float* __restrict__ v2p,
    const float* __restrict__ Jp, f2* __restrict__ S, f2* __restrict__ T) {
    __shared__ __align__(16) f2 WT[3][16];
    int b = blockIdx.x, t = threadIdx.x;
    int lane = t & 63, w = t >> 6;
    int n = b * 256 + t;
    f2 X[16];
    expmU(ux[n], uy[n], *v1p, *v2p, *Jp, X);
    wave_scan(X, lane);
    block_combine(X, WT, w, lane); // X = U_n ... U_{256b}
#pragma unroll
    for (int j = 0; j < 16; ++j) S[(size_t)j * NSAMP + n] = X[j];
    if (t == 255) st16(T + (size_t)b * 16, X);
}

// ---------- kB: redundant totals-scan -> prefix cols; load S; apply; out ----------
__global__ __launch_bounds__(256) void kB_apply(
    const f2* __restrict__ S, const f2* __restrict__ T,
    float* __restrict__ out) {
    __shared__ __align__(16) f2 WT[3][16];
    __shared__ __align__(16) f2 WB[8];
    int b = blockIdx.x, t = threadIdx.x;
    int lane = t & 63, w = t >> 6;

    // scan the 256 block totals (32 KB, L2-resident) — every block redundantly
    f2 Xt[16];
    ld16(Xt, T + (size_t)t * 16);
    wave_scan(Xt, lane);
    block_combine(Xt, WT, w, lane); // thread t: T_t * ... * T_0
    if (b == 0) {
        if (t == 0) {
#pragma unroll
            for (int i = 0; i < 8; ++i) WB[i] = (f2){0.f, 0.f};
            WB[0] = (f2){1.f, 0.f}; // col0 of I
            WB[7] = (f2){1.f, 0.f}; // col3 of I
        }
    } else if (t == b - 1) { // inclusive at b-1 = exclusive prefix for block b
#pragma unroll
        for (int a = 0; a < 4; ++a) {
            WB[a]     = Xt[a * 4 + 0];
            WB[4 + a] = Xt[a * 4 + 3];
        }
    }
    __syncthreads();

    // load this sample's in-block scan matrix, apply prefix cols, measure
    int n = b * 256 + t;
    f2 M[16];
#pragma unroll
    for (int j = 0; j < 16; ++j) M[j] = S[(size_t)j * NSAMP + n];
    f2 wv[8];
#pragma unroll
    for (int i = 0; i < 8; ++i) wv[i] = WB[i];
    mv2p(M, wv); // cols 0,3 of inclusive product P_n
    out[n] = measure(wv);
}

extern "C" void kernel_launch(void* const* d_in, const int* in_sizes, int n_in,
                              void* d_out, int out_size, void* d_ws, size_t ws_size,
                              hipStream_t stream) {
    const float* ux = (const float*)d_in[0];
    const float* uy = (const float*)d_in[1];
    const float* v1 = (const float*)d_in[2];
    const float* v2 = (const float*)d_in[3];
    const float* J  = (const float*)d_in[4];
    float* out = (float*)d_out;

    char* ws = (char*)d_ws;
    // layout: S (16 planes * 65536 f2 = 8 MiB) | T (256 * 128B = 32 KiB)
    f2* S = (f2*)(ws);
    f2* T = (f2*)(ws + (size_t)16 * NSAMP * 8);

    kA_scan<<<256, 256, 0, stream>>>(ux, uy, v1, v2, J, S, T);
    kB_apply<<<256, 256, 0, stream>>>(S, T, out);
}

// Round 8
// 23.531 us; speedup vs baseline: 3.1524x; 1.0312x over previous
//
#include <hip/hip_runtime.h>

#define NSAMP 65536
#define DTF 1e-5f

// packed complex: f2.x = re, f2.y = im ; ops lower to v_pk_fma_f32 (VOP3P)
typedef float f2 __attribute__((ext_vector_type(2)));

// (-b.im, b.re) — the "i*b" swizzle used to form packed complex FMA
__device__ __forceinline__ f2 ib(f2 b) { return (f2){-b.y, b.x}; }

// acc += a*b given precomputed bn = ib(b): two packed FMAs
// (complex mult is commutative: 'a' supplies the scalar lanes, 'b'/'bn' the vectors)
__device__ __forceinline__ f2 cmac_p(f2 acc, f2 a, f2 b, f2 bn) {
    acc = a.y * bn + acc; // (-ay*by, ay*bx) + acc
    acc = a.x * b + acc;  // (ax*bx, ax*by) + ...
    return acc;
}

// ---------- 4x4 complex matmul C = A*B (row-major, 16 f2), packed ----------
__device__ __forceinline__ void mm4p(const f2* A, const f2* B, f2* C) {
    f2 BN[16];
#pragma unroll
    for (int i = 0; i < 16; ++i) BN[i] = ib(B[i]);
#pragma unroll
    for (int a = 0; a < 4; ++a) {
#pragma unroll
        for (int b = 0; b < 4; ++b) {
            f2 acc = (f2){0.f, 0.f};
#pragma unroll
            for (int k = 0; k < 4; ++k)
                acc = cmac_p(acc, A[a * 4 + k], B[k * 4 + b], BN[k * 4 + b]);
            C[a * 4 + b] = acc;
        }
    }
}

// C = A*X where A is loop-invariant and AN = ib(A) precomputed (X scalar-side)
__device__ __forceinline__ void mm4p_Af(const f2* A, const f2* AN, const f2* X,
                                        f2* C) {
#pragma unroll
    for (int a = 0; a < 4; ++a) {
#pragma unroll
        for (int b = 0; b < 4; ++b) {
            f2 acc = (f2){0.f, 0.f};
#pragma unroll
            for (int k = 0; k < 4; ++k)
                acc = cmac_p(acc, X[k * 4 + b], A[a * 4 + k], AN[a * 4 + k]);
            C[a * 4 + b] = acc;
        }
    }
}

// two matvecs: w[0..3] <- M*w[0..3], w[4..7] <- M*w[4..7] (packed)
__device__ __forceinline__ void mv2p(const f2* M, f2* w) {
    f2 WN[8];
#pragma unroll
    for (int i = 0; i < 8; ++i) WN[i] = ib(w[i]);
    f2 r[8];
#pragma unroll
    for (int a = 0; a < 4; ++a) {
        f2 a0 = (f2){0.f, 0.f}, a1 = (f2){0.f, 0.f};
#pragma unroll
        for (int k = 0; k < 4; ++k) {
            a0 = cmac_p(a0, M[a * 4 + k], w[k], WN[k]);
            a1 = cmac_p(a1, M[a * 4 + k], w[4 + k], WN[4 + k]);
        }
        r[a] = a0;
        r[4 + a] = a1;
    }
#pragma unroll
    for (int i = 0; i < 8; ++i) w[i] = r[i];
}

// ---------- 16-f2 (128B) moves for 16B-aligned buffers ----------
__device__ __forceinline__ void ld16(f2* X, const f2* p) {
    const float4* q = (const float4*)p;
#pragma unroll
    for (int i = 0; i < 8; ++i) {
        float4 t = q[i];
        X[2 * i]     = (f2){t.x, t.y};
        X[2 * i + 1] = (f2){t.z, t.w};
    }
}
__device__ __forceinline__ void st16(f2* p, const f2* X) {
    float4* q = (float4*)p;
#pragma unroll
    for (int i = 0; i < 8; ++i)
        q[i] = make_float4(X[2 * i].x, X[2 * i].y, X[2 * i + 1].x, X[2 * i + 1].y);
}

// ---------- U = exp(-i*dt*H): order-6 Taylor, no scaling (||dtH|| <= ~0.4) ----------
// truncation <= 0.41^7/5040 ~ 4e-7 at the 4.3-sigma RF tail; fp32 noise dominates.
__device__ __forceinline__ void expmU(float uxi, float uyi, float v1, float v2,
                                      float J, f2* X) {
    const float twopi = 6.2831855f;
    float d0 = twopi * (0.5f * (v1 + v2) + 0.25f * J);
    float d1 = twopi * (0.5f * (v1 - v2) - 0.25f * J);
    float d2 = twopi * (0.5f * (v2 - v1) - 0.25f * J);
    float d3 = twopi * (-0.5f * (v1 + v2) + 0.25f * J);
    float g  = twopi * 0.5f * J;
    float cr = 0.5f * uxi;
    float ci = -0.5f * uyi;

    // H (Hermitian):
    // [d0,  c,  c,  0 ]
    // [c*, d1,  g,  c ]
    // [c*,  g, d2,  c ]
    // [ 0, c*, c*, d3 ]
    f2 H[16];
    H[0]  = (f2){d0, 0.f};  H[1]  = (f2){cr, ci};
    H[2]  = (f2){cr, ci};   H[3]  = (f2){0.f, 0.f};
    H[4]  = (f2){cr, -ci};  H[5]  = (f2){d1, 0.f};
    H[6]  = (f2){g, 0.f};   H[7]  = (f2){cr, ci};
    H[8]  = (f2){cr, -ci};  H[9]  = (f2){g, 0.f};
    H[10] = (f2){d2, 0.f};  H[11] = (f2){cr, ci};
    H[12] = (f2){0.f, 0.f}; H[13] = (f2){cr, -ci};
    H[14] = (f2){cr, -ci};  H[15] = (f2){d3, 0.f};

    // A = -i * dt * H : (-i)*(hr + i*hi) = hi - i*hr
    const float s = DTF;
    f2 A[16], AN[16];
#pragma unroll
    for (int k = 0; k < 16; ++k) {
        A[k]  = (f2){s * H[k].y, -s * H[k].x};
        AN[k] = ib(A[k]);
    }

    // order-6 Taylor via Horner: X = I + A/6; X = I + (A/k)*X, k=5..1
#pragma unroll
    for (int k = 0; k < 16; ++k) X[k] = A[k] * (1.f / 6.f);
    X[0].x += 1.f; X[5].x += 1.f; X[10].x += 1.f; X[15].x += 1.f;
#pragma unroll
    for (int kk = 5; kk >= 1; --kk) {
        f2 Z[16];
        mm4p_Af(A, AN, X, Z);
        float r = 1.0f / (float)kk;
#pragma unroll
        for (int k = 0; k < 16; ++k) X[k] = Z[k] * r;
        X[0].x += 1.f; X[5].x += 1.f; X[10].x += 1.f; X[15].x += 1.f;
    }
}

// ---------- barrier-free 64-lane inclusive matrix scan via shfl_up ----------
// combine newer-on-the-left: X_l <- X_l * X_{l-off}
__device__ __forceinline__ void wave_scan(f2* X, int lane) {
#pragma unroll
    for (int off = 1; off < 64; off <<= 1) {
        f2 Y[16];
#pragma unroll
        for (int j = 0; j < 16; ++j) {
            Y[j].x = __shfl_up(X[j].x, (unsigned)off, 64);
            Y[j].y = __shfl_up(X[j].y, (unsigned)off, 64);
        }
        if (lane >= off) {
            f2 Z[16];
            mm4p(X, Y, Z);
#pragma unroll
            for (int j = 0; j < 16; ++j) X[j] = Z[j];
        }
    }
}

// progressive cross-wave combine inside a 256-thread block.
// WT[w] (w=0..2) holds wave w's total. Wave w multiplies by WT[w-1..0].
__device__ __forceinline__ void block_combine(f2* X, f2 (*WT)[16],
                                              int w, int lane) {
    if (w < 3 && lane == 63) st16(&WT[w][0], X);
    __syncthreads();
    for (int k = w - 1; k >= 0; --k) {
        f2 Y[16], Z[16];
        ld16(Y, &WT[k][0]);
        mm4p(X, Y, Z);
#pragma unroll
        for (int j = 0; j < 16; ++j) X[j] = Z[j];
    }
}

// measurement: wv = cols 0,3 of P -> Re(0.25*(rho01+rho02+rho13+rho23))
// Re(a*conj(b)) = a.x*b.x + a.y*b.y
__device__ __forceinline__ float rec(f2 a, f2 b) { return a.x * b.x + a.y * b.y; }
__device__ __forceinline__ float measure(const f2* wv) {
    float re0 = rec(wv[0], wv[1]) + rec(wv[0], wv[2]) +
                rec(wv[1], wv[3]) + rec(wv[2], wv[3]);
    float re3 = rec(wv[4], wv[5]) + rec(wv[4], wv[6]) +
                rec(wv[5], wv[7]) + rec(wv[6], wv[7]);
    return 0.25f * (re0 - re3);
}

// ---------- kA: expm + in-block scan; store S (SoA planes) + block totals T ----------
__global__ __launch_bounds__(256) void kA_scan(
    const float* __restrict__ ux, const float* __restrict__ uy,
    const float* __restrict__ v1p, const float* __restrict__ v2p,
    const float* __restrict__ Jp, f2* __restrict__ S, f2* __restrict__ T) {
    __shared__ __align__(16) f2 WT[3][16];
    int b = blockIdx.x, t = threadIdx.x;
    int lane = t & 63, w = t >> 6;
    int n = b * 256 + t;
    f2 X[16];
    expmU(ux[n], uy[n], *v1p, *v2p, *Jp, X);
    wave_scan(X, lane);
    block_combine(X, WT, w, lane); // X = U_n ... U_{256b}
#pragma unroll
    for (int j = 0; j < 16; ++j) S[(size_t)j * NSAMP + n] = X[j];
    if (t == 255) st16(T + (size_t)b * 16, X);
}

// ---------- kB: redundant totals-scan -> prefix cols; load S; apply; out ----------
__global__ __launch_bounds__(256) void kB_apply(
    const f2* __restrict__ S, const f2* __restrict__ T,
    float* __restrict__ out) {
    __shared__ __align__(16) f2 WT[3][16];
    __shared__ __align__(16) f2 WB[8];
    int b = blockIdx.x, t = threadIdx.x;
    int lane = t & 63, w = t >> 6;

    // scan the 256 block totals (32 KB, L2-resident) — every block redundantly
    f2 Xt[16];
    ld16(Xt, T + (size_t)t * 16);
    wave_scan(Xt, lane);
    block_combine(Xt, WT, w, lane); // thread t: T_t * ... * T_0
    if (b == 0) {
        if (t == 0) {
#pragma unroll
            for (int i = 0; i < 8; ++i) WB[i] = (f2){0.f, 0.f};
            WB[0] = (f2){1.f, 0.f}; // col0 of I
            WB[7] = (f2){1.f, 0.f}; // col3 of I
        }
    } else if (t == b - 1) { // inclusive at b-1 = exclusive prefix for block b
#pragma unroll
        for (int a = 0; a < 4; ++a) {
            WB[a]     = Xt[a * 4 + 0];
            WB[4 + a] = Xt[a * 4 + 3];
        }
    }
    __syncthreads();

    // load this sample's in-block scan matrix, apply prefix cols, measure
    int n = b * 256 + t;
    f2 M[16];
#pragma unroll
    for (int j = 0; j < 16; ++j) M[j] = S[(size_t)j * NSAMP + n];
    f2 wv[8];
#pragma unroll
    for (int i = 0; i < 8; ++i) wv[i] = WB[i];
    mv2p(M, wv); // cols 0,3 of inclusive product P_n
    out[n] = measure(wv);
}

extern "C" void kernel_launch(void* const* d_in, const int* in_sizes, int n_in,
                              void* d_out, int out_size, void* d_ws, size_t ws_size,
                              hipStream_t stream) {
    const float* ux = (const float*)d_in[0];
    const float* uy = (const float*)d_in[1];
    const float* v1 = (const float*)d_in[2];
    const float* v2 = (const float*)d_in[3];
    const float* J  = (const float*)d_in[4];
    float* out = (float*)d_out;

    char* ws = (char*)d_ws;
    // layout: S (16 planes * 65536 f2 = 8 MiB) | T (256 * 128B = 32 KiB)
    f2* S = (f2*)(ws);
    f2* T = (f2*)(ws + (size_t)16 * NSAMP * 8);

    kA_scan<<<256, 256, 0, stream>>>(ux, uy, v1, v2, J, S, T);
    kB_apply<<<256, 256, 0, stream>>>(S, T, out);
}